// Round 3
// baseline (1431.791 us; speedup 1.0000x reference)
//
#include <hip/hip_runtime.h>
#include <math.h>

#define D 4096
#define E_EXPERTS 64
#define NTOK 32768
#define BM 64
#define BK 32
#define NTHREADS 256
#define AS_LD 65
#define BS_LD 65
#define L_LD 65
#define SMEM_FLOATS 4440
#define TAU 2.5e-4f

// out layout (float32):
//   [0,65536)          top_k_indices as float
//   [65536,131072)     top_k_weights
//   [131072]           balance_loss
//   [131073]           z_loss
//   [131074,131138)    tokens_per_expert
// ws layout (float32): [0,64) counts, [64,128) prob sums, [128] lse sum

__global__ __launch_bounds__(NTHREADS)
void moe_router_main(const float* __restrict__ x,
                     const float* __restrict__ gw,
                     float* __restrict__ out,
                     float* __restrict__ ws) {
  __shared__ float smem[SMEM_FLOATS];
  float* As = smem;                   // [BK][AS_LD] transposed A tile (k-major)
  float* Bs = smem + BK * AS_LD;      // [BK][BS_LD] transposed W tile

  const int tid = threadIdx.x;
  const int bid = blockIdx.x;
  const int t0 = bid * BM;

  const int tm0 = (tid >> 4) << 2;    // 4 tokens per thread
  const int tn0 = (tid & 15) << 2;    // 4 experts per thread

  float acc[4][4];
#pragma unroll
  for (int i = 0; i < 4; ++i)
#pragma unroll
    for (int j = 0; j < 4; ++j) acc[i][j] = 0.0f;

  const float* xA = x + (size_t)t0 * D;

  // per-thread staging assignments: 2 float4 for A, 2 for B
  float4 pa[2], pb[2];
  int aRow[2], aCol[2], bRow[2], bCol[2];
#pragma unroll
  for (int r = 0; r < 2; ++r) {
    int idx = tid + r * NTHREADS;
    aRow[r] = idx >> 3;          // token 0..63
    aCol[r] = (idx & 7) << 2;    // k offset 0..28
    bRow[r] = idx >> 3;          // expert 0..63
    bCol[r] = (idx & 7) << 2;
    pa[r] = *(const float4*)(xA + (size_t)aRow[r] * D + aCol[r]);
    pb[r] = *(const float4*)(gw + (size_t)bRow[r] * D + bCol[r]);
  }

  const int NKT = D / BK;  // 128
  for (int kt = 0; kt < NKT; ++kt) {
    // store prefetched tile to LDS (transposed, pad 65 -> ~2-way conflicts)
#pragma unroll
    for (int r = 0; r < 2; ++r) {
      float* p = As + aCol[r] * AS_LD + aRow[r];
      p[0 * AS_LD] = pa[r].x;
      p[1 * AS_LD] = pa[r].y;
      p[2 * AS_LD] = pa[r].z;
      p[3 * AS_LD] = pa[r].w;
      float* q = Bs + bCol[r] * BS_LD + bRow[r];
      q[0 * BS_LD] = pb[r].x;
      q[1 * BS_LD] = pb[r].y;
      q[2 * BS_LD] = pb[r].z;
      q[3 * BS_LD] = pb[r].w;
    }
    __syncthreads();

    // issue next-tile global loads (hide HBM latency under the FMA block)
    if (kt + 1 < NKT) {
      const int k0 = (kt + 1) * BK;
#pragma unroll
      for (int r = 0; r < 2; ++r) {
        pa[r] = *(const float4*)(xA + (size_t)aRow[r] * D + k0 + aCol[r]);
        pb[r] = *(const float4*)(gw + (size_t)bRow[r] * D + k0 + bCol[r]);
      }
    }

    // compute current tile
#pragma unroll
    for (int kk = 0; kk < BK; ++kk) {
      float4 av = *(const float4*)(As + kk * AS_LD + tm0);
      float4 bv = *(const float4*)(Bs + kk * BS_LD + tn0);
      float a[4] = {av.x, av.y, av.z, av.w};
      float b[4] = {bv.x, bv.y, bv.z, bv.w};
#pragma unroll
      for (int i = 0; i < 4; ++i)
#pragma unroll
        for (int j = 0; j < 4; ++j)
          acc[i][j] = fmaf(a[i], b[j], acc[i][j]);
    }
    __syncthreads();
  }

  // ---------------- epilogue: logits -> LDS, per-token stats ----------------
  float* L = smem;                       // [BM][L_LD]
  float* mArr = smem + BM * L_LD;        // [BM]
  float* zArr = mArr + BM;               // [BM] holds 1/Z
  float* cntL = zArr + BM;               // [E]
  float* probA = cntL + E_EXPERTS;       // [E]
  float* red = probA + E_EXPERTS;        // [8]

#pragma unroll
  for (int i = 0; i < 4; ++i)
#pragma unroll
    for (int j = 0; j < 4; ++j)
      L[(tm0 + i) * L_LD + tn0 + j] = acc[i][j];
  if (tid < E_EXPERTS) {
    cntL[tid] = 0.0f;
    probA[tid] = 0.0f;
  }
  __syncthreads();

  float lseVal = 0.0f;
  if (tid < BM) {  // exactly wave 0
    const int lane = tid;
    const float* row = L + tid * L_LD;
    // top-3 scan (jax top_k tie-break: lower index first)
    float m1 = -3.4e38f, m2 = -3.4e38f, m3 = -3.4e38f;
    int i1 = 0, i2 = 0, i3 = 0;
    for (int e = 0; e < E_EXPERTS; ++e) {
      float v = row[e];
      if (v > m1) {
        m3 = m2; i3 = i2;
        m2 = m1; i2 = i1;
        m1 = v;  i1 = e;
      } else if (v > m2) {
        m3 = m2; i3 = i2;
        m2 = v;  i2 = e;
      } else if (v > m3) {
        m3 = v; i3 = e;
      }
    }
    float z = 0.0f;
    for (int e = 0; e < E_EXPERTS; ++e) z += __expf(row[e] - m1);
    mArr[tid] = m1;
    zArr[tid] = 1.0f / z;
    lseVal = m1 + logf(z);

    // ---- fp64 refinement of near-ties (wave-cooperative, rare) ----
    bool risky = (m1 - m2 < TAU) || (m2 - m3 < TAU);
    double r1 = 0.0, r2 = 0.0, r3 = 0.0;
    unsigned long long mask = __ballot(risky);
    while (mask) {
      int src = __ffsll((long long)mask) - 1;
      mask &= (mask - 1);
      int tok = t0 + src;
      int j1 = __shfl(i1, src, 64);
      int j2 = __shfl(i2, src, 64);
      int j3 = __shfl(i3, src, 64);
      const float* xr = x + (size_t)tok * D;
      const float* g1 = gw + (size_t)j1 * D;
      const float* g2 = gw + (size_t)j2 * D;
      const float* g3 = gw + (size_t)j3 * D;
      double a1 = 0.0, a2 = 0.0, a3 = 0.0;
      for (int k = lane * 4; k < D; k += 256) {
        float4 xv = *(const float4*)(xr + k);
        float4 w1 = *(const float4*)(g1 + k);
        float4 w2 = *(const float4*)(g2 + k);
        float4 w3 = *(const float4*)(g3 + k);
        a1 += (double)xv.x * w1.x + (double)xv.y * w1.y +
              (double)xv.z * w1.z + (double)xv.w * w1.w;
        a2 += (double)xv.x * w2.x + (double)xv.y * w2.y +
              (double)xv.z * w2.z + (double)xv.w * w2.w;
        a3 += (double)xv.x * w3.x + (double)xv.y * w3.y +
              (double)xv.z * w3.z + (double)xv.w * w3.w;
      }
#pragma unroll
      for (int off = 32; off > 0; off >>= 1) {
        a1 += __shfl_down(a1, off, 64);
        a2 += __shfl_down(a2, off, 64);
        a3 += __shfl_down(a3, off, 64);
      }
      a1 = __shfl(a1, 0, 64);
      a2 = __shfl(a2, 0, 64);
      a3 = __shfl(a3, 0, 64);
      if (lane == src) { r1 = a1; r2 = a2; r3 = a3; }
    }

    float wOut1, wOut2;
    if (risky) {
      double v[3] = {r1, r2, r3};
      int ix[3] = {i1, i2, i3};
#define SORT_SWAP(a, b)                                                  \
      if (v[b] > v[a] || (v[b] == v[a] && ix[b] < ix[a])) {              \
        double tv = v[a]; v[a] = v[b]; v[b] = tv;                        \
        int ti = ix[a]; ix[a] = ix[b]; ix[b] = ti;                       \
      }
      SORT_SWAP(0, 1);
      SORT_SWAP(1, 2);
      SORT_SWAP(0, 1);
#undef SORT_SWAP
      i1 = ix[0]; i2 = ix[1];
      double d = exp(v[1] - v[0]);
      wOut1 = (float)(1.0 / (1.0 + d));
      wOut2 = (float)(d / (1.0 + d));
    } else {
      float e2 = __expf(m2 - m1);
      wOut1 = 1.0f / (1.0f + e2);
      wOut2 = e2 * wOut1;
    }

    size_t ot = ((size_t)t0 + tid) * 2;
    out[ot] = (float)i1;
    out[ot + 1] = (float)i2;
    out[(size_t)NTOK * 2 + ot] = wOut1;
    out[(size_t)NTOK * 2 + ot + 1] = wOut2;

    atomicAdd(&cntL[i1], 1.0f);
    atomicAdd(&cntL[i2], 1.0f);

    // wave-0 lse reduction
    float v = lseVal;
#pragma unroll
    for (int off = 32; off > 0; off >>= 1) v += __shfl_down(v, off, 64);
    if (tid == 0) atomicAdd(&ws[128], v);
  }
  __syncthreads();
  if (tid < E_EXPERTS) atomicAdd(&ws[tid], cntL[tid]);

  // per-expert prob sums: thread (e, q) sums 16 tokens
  {
    const int e = tid & 63;
    const int q = tid >> 6;
    float s = 0.0f;
    for (int t = q * 16; t < q * 16 + 16; ++t)
      s += __expf(L[t * L_LD + e] - mArr[t]) * zArr[t];
    atomicAdd(&probA[e], s);
  }
  __syncthreads();
  if (tid < E_EXPERTS) atomicAdd(&ws[64 + tid], probA[tid]);
}

__global__ void moe_finalize(const float* __restrict__ ws,
                             float* __restrict__ out) {
  const int e = threadIdx.x;  // 64 threads
  const float inv_n = 1.0f / (float)NTOK;
  float tpe = ws[e] * inv_n;
  out[131074 + e] = tpe;
  float rppe = ws[64 + e] * inv_n;
  float part = tpe * rppe;
#pragma unroll
  for (int off = 32; off > 0; off >>= 1) part += __shfl_down(part, off, 64);
  if (e == 0) {
    out[131072] = part * 64.0f * 0.01f;
    float meanLse = ws[128] * inv_n;
    out[131073] = meanLse * meanLse * 0.001f;
  }
}

extern "C" void kernel_launch(void* const* d_in, const int* in_sizes, int n_in,
                              void* d_out, int out_size, void* d_ws, size_t ws_size,
                              hipStream_t stream) {
  const float* x = (const float*)d_in[0];
  const float* gw = (const float*)d_in[1];
  float* out = (float*)d_out;
  float* ws = (float*)d_ws;

  hipMemsetAsync(d_ws, 0, 129 * sizeof(float), stream);
  hipLaunchKernelGGL(moe_router_main, dim3(NTOK / BM), dim3(NTHREADS), 0, stream,
                     x, gw, out, ws);
  hipLaunchKernelGGL(moe_finalize, dim3(1), dim3(E_EXPERTS), 0, stream, ws, out);
}

// Round 4
// 178.584 us; speedup vs baseline: 8.0175x; 8.0175x over previous
//
#include <hip/hip_runtime.h>
#include <math.h>

#define D 4096
#define E_EXPERTS 64
#define NTOK 32768
#define BM 128
#define BK 32
#define NTHREADS 256
#define NKT (D / BK)   /* 128 */
#define L_LD 65
#define SMEM_FLOATS 8712
#define TAU 2.5e-4f

// LDS staging byte offsets (inside smem), all 16B-aligned:
#define AH_OFF 0
#define A_OSTRIDE 2112   /* 128*16 + 64 pad per k-oct */
#define AL_OFF 8448      /* 4*2112 */
#define BH_OFF 16896
#define B_OSTRIDE 1088   /* 64*16 + 64 pad per k-oct */
#define BL_OFF 21248     /* total staging = 25600 B < 34848 B smem */

// out layout (float32):
//   [0,65536) indices, [65536,131072) weights,
//   [131072] balance_loss, [131073] z_loss, [131074,131138) tokens_per_expert
// ws: [0,64) counts, [64,128) prob sums, [128] lse sum

typedef float f32x4 __attribute__((ext_vector_type(4)));
typedef short short8v __attribute__((ext_vector_type(8)));

__device__ __forceinline__ unsigned short f2bf_rne(float f) {
  unsigned u = __builtin_bit_cast(unsigned, f);
  unsigned r = (u + 0x7fffu + ((u >> 16) & 1u)) >> 16;
  return (unsigned short)r;
}
__device__ __forceinline__ float bf2f(unsigned short h) {
  unsigned u = ((unsigned)h) << 16;
  return __builtin_bit_cast(float, u);
}
__device__ __forceinline__ void cvt_pack(float4 v, unsigned long long* hp,
                                         unsigned long long* lp) {
  float f[4] = {v.x, v.y, v.z, v.w};
  unsigned long long h = 0ull, lo = 0ull;
#pragma unroll
  for (int i = 0; i < 4; ++i) {
    unsigned short hs = f2bf_rne(f[i]);
    unsigned short ls = f2bf_rne(f[i] - bf2f(hs));
    h |= ((unsigned long long)hs) << (16 * i);
    lo |= ((unsigned long long)ls) << (16 * i);
  }
  *hp = h;
  *lp = lo;
}

__global__ __launch_bounds__(NTHREADS)
void moe_router_main(const float* __restrict__ x,
                     const float* __restrict__ gw,
                     float* __restrict__ out,
                     float* __restrict__ ws) {
  __shared__ float smem[SMEM_FLOATS];
  char* sb = (char*)smem;

  const int tid = threadIdx.x;
  const int bid = blockIdx.x;
  const int t0 = bid * BM;
  const int w = tid >> 6;     // wave 0..3 -> tokens [w*32, w*32+32)
  const int l = tid & 63;

  const float* xA = x + (size_t)t0 * D;

  // ---- staging assignments (per thread): A 4 float4-slots, B 2 ----
  size_t aG[4];
  int aL[4];
#pragma unroll
  for (int r = 0; r < 4; ++r) {
    int f = tid + r * NTHREADS;       // 0..1023
    int t = f >> 3, q = f & 7;        // token, float4-in-row
    aG[r] = (size_t)t * D + q * 4;
    aL[r] = (q >> 1) * A_OSTRIDE + t * 16 + (q & 1) * 8;
  }
  size_t bG[2];
  int bL[2];
#pragma unroll
  for (int r = 0; r < 2; ++r) {
    int f = tid + r * NTHREADS;       // 0..511
    int e = f >> 3, q = f & 7;
    bG[r] = (size_t)e * D + q * 4;
    bL[r] = (q >> 1) * B_OSTRIDE + e * 16 + (q & 1) * 8;
  }

  // ---- fragment read offsets (per lane) ----
  const int c4 = l >> 4, rb = l & 15;
  const int abase = c4 * A_OSTRIDE + (w * 32 + rb) * 16;
  const int aoffH0 = AH_OFF + abase;
  const int aoffH1 = AH_OFF + abase + 256;  // +16 tokens
  const int aoffL0 = AL_OFF + abase;
  const int aoffL1 = AL_OFF + abase + 256;
  int boffH[4], boffL[4];
#pragma unroll
  for (int n = 0; n < 4; ++n) {
    int bb = c4 * B_OSTRIDE + (n * 16 + rb) * 16;
    boffH[n] = BH_OFF + bb;
    boffL[n] = BL_OFF + bb;
  }

  f32x4 acc[2][4];
#pragma unroll
  for (int m = 0; m < 2; ++m)
#pragma unroll
    for (int n = 0; n < 4; ++n)
      acc[m][n] = (f32x4){0.f, 0.f, 0.f, 0.f};

#define LOAD_SET(pa, pb, kt)                                   \
  {                                                            \
    const int k0_ = (kt)*BK;                                   \
    _Pragma("unroll") for (int r = 0; r < 4; ++r)              \
        pa[r] = *(const float4*)(xA + aG[r] + k0_);            \
    _Pragma("unroll") for (int r = 0; r < 2; ++r)              \
        pb[r] = *(const float4*)(gw + bG[r] + k0_);            \
  }

#define STORE_SET(pa, pb)                                      \
  {                                                            \
    _Pragma("unroll") for (int r = 0; r < 4; ++r) {            \
      unsigned long long hp, lp;                               \
      cvt_pack(pa[r], &hp, &lp);                               \
      *(unsigned long long*)(sb + AH_OFF + aL[r]) = hp;        \
      *(unsigned long long*)(sb + AL_OFF + aL[r]) = lp;        \
    }                                                          \
    _Pragma("unroll") for (int r = 0; r < 2; ++r) {            \
      unsigned long long hp, lp;                               \
      cvt_pack(pb[r], &hp, &lp);                               \
      *(unsigned long long*)(sb + BH_OFF + bL[r]) = hp;        \
      *(unsigned long long*)(sb + BL_OFF + bL[r]) = lp;        \
    }                                                          \
  }

#define COMPUTE_STEP()                                                        \
  {                                                                           \
    short8v ah0 = *(const short8v*)(sb + aoffH0);                             \
    short8v ah1 = *(const short8v*)(sb + aoffH1);                             \
    short8v al0 = *(const short8v*)(sb + aoffL0);                             \
    short8v al1 = *(const short8v*)(sb + aoffL1);                             \
    _Pragma("unroll") for (int n = 0; n < 4; ++n) {                           \
      short8v bh = *(const short8v*)(sb + boffH[n]);                          \
      short8v bl = *(const short8v*)(sb + boffL[n]);                          \
      acc[0][n] =                                                             \
          __builtin_amdgcn_mfma_f32_16x16x32_bf16(ah0, bh, acc[0][n], 0, 0, 0); \
      acc[0][n] =                                                             \
          __builtin_amdgcn_mfma_f32_16x16x32_bf16(ah0, bl, acc[0][n], 0, 0, 0); \
      acc[0][n] =                                                             \
          __builtin_amdgcn_mfma_f32_16x16x32_bf16(al0, bh, acc[0][n], 0, 0, 0); \
      acc[1][n] =                                                             \
          __builtin_amdgcn_mfma_f32_16x16x32_bf16(ah1, bh, acc[1][n], 0, 0, 0); \
      acc[1][n] =                                                             \
          __builtin_amdgcn_mfma_f32_16x16x32_bf16(ah1, bl, acc[1][n], 0, 0, 0); \
      acc[1][n] =                                                             \
          __builtin_amdgcn_mfma_f32_16x16x32_bf16(al1, bh, acc[1][n], 0, 0, 0); \
    }                                                                         \
  }

  float4 pa0[4], pb0[2], pa1[4], pb1[2];
  LOAD_SET(pa0, pb0, 0);
  LOAD_SET(pa1, pb1, 1);

  for (int kt = 0; kt < NKT; kt += 2) {
    STORE_SET(pa0, pb0);
    __syncthreads();
    if (kt + 2 < NKT) LOAD_SET(pa0, pb0, kt + 2);
    COMPUTE_STEP();
    __syncthreads();

    STORE_SET(pa1, pb1);
    __syncthreads();
    if (kt + 3 < NKT) LOAD_SET(pa1, pb1, kt + 3);
    COMPUTE_STEP();
    __syncthreads();
  }

  // ---- write logits to LDS L[128][65] ----
  // D layout (verified m89/m91): col = lane&15, row = (lane>>4)*4 + reg
#pragma unroll
  for (int m = 0; m < 2; ++m)
#pragma unroll
    for (int n = 0; n < 4; ++n)
#pragma unroll
      for (int r = 0; r < 4; ++r) {
        int row = w * 32 + m * 16 + c4 * 4 + r;
        int col = n * 16 + rb;
        smem[row * L_LD + col] = acc[m][n][r];
      }

  float* L = smem;                   // [BM][65]
  float* mArr = smem + BM * L_LD;    // [BM]
  float* zArr = mArr + BM;           // [BM] 1/Z
  float* cntL = zArr + BM;           // [64]
  float* probA = cntL + E_EXPERTS;   // [64]
  float* red = probA + E_EXPERTS;    // [8]
  if (tid < E_EXPERTS) {
    cntL[tid] = 0.0f;
    probA[tid] = 0.0f;
  }
  __syncthreads();

  float lseVal = 0.0f;
  if (tid < BM) {
    const int lane = tid & 63;
    const float* row = L + tid * L_LD;
    float m1 = -3.4e38f, m2 = -3.4e38f, m3 = -3.4e38f;
    int i1 = 0, i2 = 0, i3 = 0;
    for (int e = 0; e < E_EXPERTS; ++e) {
      float v = row[e];
      if (v > m1) {
        m3 = m2; i3 = i2;
        m2 = m1; i2 = i1;
        m1 = v;  i1 = e;
      } else if (v > m2) {
        m3 = m2; i3 = i2;
        m2 = v;  i2 = e;
      } else if (v > m3) {
        m3 = v; i3 = e;
      }
    }
    float z = 0.0f;
    for (int e = 0; e < E_EXPERTS; ++e) z += __expf(row[e] - m1);
    mArr[tid] = m1;
    zArr[tid] = 1.0f / z;
    lseVal = m1 + logf(z);

    // ---- fp64 refinement of near-ties (rare) ----
    bool risky = (m1 - m2 < TAU) || (m2 - m3 < TAU);
    double r1 = 0.0, r2 = 0.0, r3 = 0.0;
    unsigned long long mask = __ballot(risky);
    while (mask) {
      int src = __ffsll((long long)mask) - 1;
      mask &= (mask - 1);
      int tok = t0 + (tid & ~63) + src;
      int j1 = __shfl(i1, src, 64);
      int j2 = __shfl(i2, src, 64);
      int j3 = __shfl(i3, src, 64);
      const float* xr = x + (size_t)tok * D;
      const float* g1 = gw + (size_t)j1 * D;
      const float* g2 = gw + (size_t)j2 * D;
      const float* g3 = gw + (size_t)j3 * D;
      double a1 = 0.0, a2 = 0.0, a3 = 0.0;
      for (int k = lane * 4; k < D; k += 256) {
        float4 xv = *(const float4*)(xr + k);
        float4 w1 = *(const float4*)(g1 + k);
        float4 w2 = *(const float4*)(g2 + k);
        float4 w3 = *(const float4*)(g3 + k);
        a1 += (double)xv.x * w1.x + (double)xv.y * w1.y +
              (double)xv.z * w1.z + (double)xv.w * w1.w;
        a2 += (double)xv.x * w2.x + (double)xv.y * w2.y +
              (double)xv.z * w2.z + (double)xv.w * w2.w;
        a3 += (double)xv.x * w3.x + (double)xv.y * w3.y +
              (double)xv.z * w3.z + (double)xv.w * w3.w;
      }
#pragma unroll
      for (int off = 32; off > 0; off >>= 1) {
        a1 += __shfl_down(a1, off, 64);
        a2 += __shfl_down(a2, off, 64);
        a3 += __shfl_down(a3, off, 64);
      }
      a1 = __shfl(a1, 0, 64);
      a2 = __shfl(a2, 0, 64);
      a3 = __shfl(a3, 0, 64);
      if (lane == src) { r1 = a1; r2 = a2; r3 = a3; }
    }

    float wOut1, wOut2;
    if (risky) {
      double v[3] = {r1, r2, r3};
      int ix[3] = {i1, i2, i3};
#define SORT_SWAP(a, b)                                            \
      if (v[b] > v[a] || (v[b] == v[a] && ix[b] < ix[a])) {        \
        double tv = v[a]; v[a] = v[b]; v[b] = tv;                  \
        int ti = ix[a]; ix[a] = ix[b]; ix[b] = ti;                 \
      }
      SORT_SWAP(0, 1);
      SORT_SWAP(1, 2);
      SORT_SWAP(0, 1);
#undef SORT_SWAP
      i1 = ix[0]; i2 = ix[1];
      double d = exp(v[1] - v[0]);
      wOut1 = (float)(1.0 / (1.0 + d));
      wOut2 = (float)(d / (1.0 + d));
    } else {
      float e2 = __expf(m2 - m1);
      wOut1 = 1.0f / (1.0f + e2);
      wOut2 = e2 * wOut1;
    }

    size_t ot = ((size_t)t0 + tid) * 2;
    out[ot] = (float)i1;
    out[ot + 1] = (float)i2;
    out[(size_t)NTOK * 2 + ot] = wOut1;
    out[(size_t)NTOK * 2 + ot + 1] = wOut2;

    atomicAdd(&cntL[i1], 1.0f);
    atomicAdd(&cntL[i2], 1.0f);
  }

  // block lse sum
  float v = lseVal;
#pragma unroll
  for (int off = 32; off > 0; off >>= 1) v += __shfl_down(v, off, 64);
  if ((tid & 63) == 0) red[tid >> 6] = v;
  __syncthreads();
  if (tid == 0) atomicAdd(&ws[128], red[0] + red[1] + red[2] + red[3]);
  if (tid < E_EXPERTS) atomicAdd(&ws[tid], cntL[tid]);

  // per-expert prob sums: thread (e, q) sums 32 tokens
  {
    const int e = tid & 63;
    const int q = tid >> 6;
    float s = 0.0f;
    for (int t = q * 32; t < q * 32 + 32; ++t)
      s += __expf(L[t * L_LD + e] - mArr[t]) * zArr[t];
    atomicAdd(&probA[e], s);
  }
  __syncthreads();
  if (tid < E_EXPERTS) atomicAdd(&ws[64 + tid], probA[tid]);
}

__global__ void moe_finalize(const float* __restrict__ ws,
                             float* __restrict__ out) {
  const int e = threadIdx.x;  // 64 threads
  const float inv_n = 1.0f / (float)NTOK;
  float tpe = ws[e] * inv_n;
  out[131074 + e] = tpe;
  float rppe = ws[64 + e] * inv_n;
  float part = tpe * rppe;
#pragma unroll
  for (int off = 32; off > 0; off >>= 1) part += __shfl_down(part, off, 64);
  if (e == 0) {
    out[131072] = part * 64.0f * 0.01f;
    float meanLse = ws[128] * inv_n;
    out[131073] = meanLse * meanLse * 0.001f;
  }
}

extern "C" void kernel_launch(void* const* d_in, const int* in_sizes, int n_in,
                              void* d_out, int out_size, void* d_ws, size_t ws_size,
                              hipStream_t stream) {
  const float* x = (const float*)d_in[0];
  const float* gw = (const float*)d_in[1];
  float* out = (float*)d_out;
  float* ws = (float*)d_ws;

  hipMemsetAsync(d_ws, 0, 129 * sizeof(float), stream);
  hipLaunchKernelGGL(moe_router_main, dim3(NTOK / BM), dim3(NTHREADS), 0, stream,
                     x, gw, out, ws);
  hipLaunchKernelGGL(moe_finalize, dim3(1), dim3(E_EXPERTS), 0, stream, ws, out);
}